// Round 3
// baseline (298.524 us; speedup 1.0000x reference)
//
#include <hip/hip_runtime.h>
#include <hip/hip_bf16.h>

#ifndef M_PI
#define M_PI 3.14159265358979323846
#endif

static constexpr int B_ = 128;   // batch
static constexpr int N_ = 3136;  // tokens
static constexpr int C_ = 96;    // channels
static constexpr int NC = N_ * C_;
static constexpr int PITCH = 104;  // fallback kernel LDS pitch

typedef short short8 __attribute__((ext_vector_type(8)));
typedef float float4v __attribute__((ext_vector_type(4)));

static __device__ __forceinline__ unsigned short f2bf(float f) {
  __hip_bfloat16 b = __float2bfloat16(f);
  return *reinterpret_cast<unsigned short*>(&b);
}

// ---------------------------------------------------------------------------
// Kernel 1: per token n, h_n = irfft(w_n, 96) (backward norm; Im of DC/Nyquist
// ignored = pocketfft c2r). Write 8 shifted bf16 replicas:
//   wsB[n][s][j] = bf16(ext_n[j + s]),  s in 0..7, j in 0..191
//   ext_n[u] = h_n[(288 - u) % 96]   (== hrev: ext[96 + k - c] = h[(c-k)%96])
// 3 KB per token; makes every MFMA B-fragment a 16B-aligned load.
// ---------------------------------------------------------------------------
__global__ __launch_bounds__(128) void gf_hbuild_kernel(
    const float* __restrict__ wc, unsigned short* __restrict__ wsB) {
  const int n = blockIdx.x;
  const int tid = threadIdx.x;
  __shared__ float wsh[98];
  __shared__ float cs[96], sn[96];
  __shared__ unsigned short hlb[96];

  if (tid < 98) wsh[tid] = wc[n * 98 + tid];
  if (tid < 96) {
    float s, c;
    sincosf((float)(2.0 * M_PI / 96.0) * (float)tid, &s, &c);
    cs[tid] = c;
    sn[tid] = s;
  }
  __syncthreads();

  if (tid < 96) {
    const int c = tid;
    float acc = wsh[0] + ((c & 1) ? -wsh[96] : wsh[96]);  // DC + Nyquist (re)
    int idx = c;
    for (int k = 1; k <= 47; ++k) {
      acc += 2.0f * (wsh[2 * k] * cs[idx] - wsh[2 * k + 1] * sn[idx]);
      idx += c;
      if (idx >= 96) idx -= 96;
    }
    hlb[c] = f2bf(acc * (1.0f / 96.0f));
  }
  __syncthreads();

  // write wsB[n][s][j] pairs as u32: e = s*96 + jp, j = 2*jp
  unsigned int* out = reinterpret_cast<unsigned int*>(wsB + (size_t)n * 1536);
  for (int e = tid; e < 768; e += 128) {
    const int s = e / 96;
    const int jp = e - s * 96;
    const int a = 288 - (2 * jp + s);       // ext index complement, a >= 89
    const unsigned int lo = hlb[a % 96];      // ext[2jp + s]
    const unsigned int hi = hlb[(a - 1) % 96];  // ext[2jp + 1 + s]
    out[e] = lo | (hi << 16);
  }
}

// ---------------------------------------------------------------------------
// Kernel 2: pure streaming MFMA, no LDS, no barriers.
// y[:,n,:] = x[:,n,:] (128x96) @ H_n (96x96 circulant), bf16 16x16x32 MFMA.
// A-frags straight from global x (32B/lane contiguous), B-frags from wsB.
// ---------------------------------------------------------------------------
__global__ __launch_bounds__(256, 4) void gf_mfma2_kernel(
    const float* __restrict__ x, const unsigned short* __restrict__ wsB,
    float* __restrict__ y) {
  const int n = blockIdx.x;
  const int tid = threadIdx.x;
  const int wv = tid >> 6;   // wave 0..3, owns M-tiles {2wv, 2wv+1}
  const int l = tid & 63;
  const int lrow = l & 15;   // A-row / B-col / C-col within tile
  const int lk = l >> 4;     // k-group

  // ---- A fragments: load x rows (fp32), convert to bf16 ----
  float4 v0[2][3], v1[2][3];
#pragma unroll
  for (int mt = 0; mt < 2; ++mt) {
    const float* xp =
        x + (size_t)((wv * 2 + mt) * 16 + lrow) * NC + n * C_ + lk * 8;
#pragma unroll
    for (int kq = 0; kq < 3; ++kq) {
      v0[mt][kq] = *reinterpret_cast<const float4*>(xp + kq * 32);
      v1[mt][kq] = *reinterpret_cast<const float4*>(xp + kq * 32 + 4);
    }
  }
  short8 afr[2][3];
#pragma unroll
  for (int mt = 0; mt < 2; ++mt)
#pragma unroll
    for (int kq = 0; kq < 3; ++kq) {
      short8 a;
      a[0] = (short)f2bf(v0[mt][kq].x);
      a[1] = (short)f2bf(v0[mt][kq].y);
      a[2] = (short)f2bf(v0[mt][kq].z);
      a[3] = (short)f2bf(v0[mt][kq].w);
      a[4] = (short)f2bf(v1[mt][kq].x);
      a[5] = (short)f2bf(v1[mt][kq].y);
      a[6] = (short)f2bf(v1[mt][kq].z);
      a[7] = (short)f2bf(v1[mt][kq].w);
      afr[mt][kq] = a;
    }

  // ---- B fragment base pointer (lane-constant; frag offsets are imms) ----
  // m = 96 + (kq*32 + lk*8) - (nt*16 + lrow); s = m&7 = M0&7 is (kq,nt)-invariant
  const int M0 = 96 + lk * 8 - lrow;
  const unsigned short* wb0 =
      wsB + (size_t)n * 1536 + (M0 & 7) * 192 + (M0 & ~7);

  float4v acc[2][6];
#pragma unroll
  for (int mt = 0; mt < 2; ++mt)
#pragma unroll
    for (int nt = 0; nt < 6; ++nt)
#pragma unroll
      for (int i = 0; i < 4; ++i) acc[mt][nt][i] = 0.0f;

#pragma unroll
  for (int nt = 0; nt < 6; ++nt) {
#pragma unroll
    for (int kq = 0; kq < 3; ++kq) {
      const short8 bfr =
          *reinterpret_cast<const short8*>(wb0 + kq * 32 - nt * 16);
      acc[0][nt] = __builtin_amdgcn_mfma_f32_16x16x32_bf16(afr[0][kq], bfr,
                                                           acc[0][nt], 0, 0, 0);
      acc[1][nt] = __builtin_amdgcn_mfma_f32_16x16x32_bf16(afr[1][kq], bfr,
                                                           acc[1][nt], 0, 0, 0);
    }
  }

  // ---- epilogue: C/D layout col = lane&15, row = (lane>>4)*4 + reg ----
#pragma unroll
  for (int mt = 0; mt < 2; ++mt) {
    const int brow0 = (wv * 2 + mt) * 16 + lk * 4;
#pragma unroll
    for (int i = 0; i < 4; ++i) {
      float* yp = y + (size_t)(brow0 + i) * NC + (size_t)n * C_;
#pragma unroll
      for (int nt = 0; nt < 6; ++nt) {
        yp[nt * 16 + lrow] = acc[mt][nt][i];
      }
    }
  }
}

// ---------------------------------------------------------------------------
// Fallback (round-2 fused kernel) if ws_size is too small for the h tables.
// ---------------------------------------------------------------------------
__global__ __launch_bounds__(256, 3) void gf_mfma_kernel(
    const float* __restrict__ x, const float* __restrict__ wc,
    float* __restrict__ y) {
  const int n = blockIdx.x;
  const int tid = threadIdx.x;

  __shared__ __align__(16) unsigned short Asm[128 * PITCH];
  __shared__ __align__(16) unsigned short Ht[96 * PITCH];
  __shared__ float wsh[98];
  __shared__ float cs[96];
  __shared__ float sn[96];
  __shared__ unsigned short hrevd[192];

  float4 xv[12];
  const float* xbase = x + (size_t)n * C_;
#pragma unroll
  for (int p = 0; p < 12; ++p) {
    const int fidx = p * 256 + tid;
    const int b = fidx / 24;
    const int t4 = fidx - b * 24;
    xv[p] = *reinterpret_cast<const float4*>(xbase + (size_t)b * NC + 4 * t4);
  }

  if (tid < 98) wsh[tid] = wc[n * 98 + tid];
  if (tid < 96) {
    float s, c;
    sincosf((float)(2.0 * M_PI / 96.0) * (float)tid, &s, &c);
    cs[tid] = c;
    sn[tid] = s;
  }
  __syncthreads();

  if (tid < 96) {
    const int c = tid;
    float acc = wsh[0] + ((c & 1) ? -wsh[96] : wsh[96]);
    int idx = c;
    for (int k = 1; k <= 47; ++k) {
      acc += 2.0f * (wsh[2 * k] * cs[idx] - wsh[2 * k + 1] * sn[idx]);
      idx += c;
      if (idx >= 96) idx -= 96;
    }
    const unsigned short hb = f2bf(acc * (1.0f / 96.0f));
    hrevd[96 - c] = hb;
    hrevd[(c == 0) ? 0 : (192 - c)] = hb;
  }

#pragma unroll
  for (int p = 0; p < 12; ++p) {
    const int fidx = p * 256 + tid;
    const int b = fidx / 24;
    const int t4 = fidx - b * 24;
    ushort4 o;
    o.x = f2bf(xv[p].x);
    o.y = f2bf(xv[p].y);
    o.z = f2bf(xv[p].z);
    o.w = f2bf(xv[p].w);
    *reinterpret_cast<ushort4*>(&Asm[b * PITCH + 4 * t4]) = o;
  }
  __syncthreads();

  for (int j = tid; j < 96 * 48; j += 256) {
    const int c = j / 48;
    const int kp = j - c * 48;
    const int m = 96 - c + 2 * kp;
    const unsigned int lo = hrevd[m];
    const unsigned int hi = hrevd[m + 1];
    *reinterpret_cast<unsigned int*>(&Ht[c * PITCH + 2 * kp]) = lo | (hi << 16);
  }
  __syncthreads();

  const int wv = tid >> 6;
  const int l = tid & 63;
  const int lrow = l & 15;
  const int lk = l >> 4;

  float4v acc[2][6];
#pragma unroll
  for (int mt = 0; mt < 2; ++mt)
#pragma unroll
    for (int nt = 0; nt < 6; ++nt)
#pragma unroll
      for (int i = 0; i < 4; ++i) acc[mt][nt][i] = 0.0f;

  short8 afr[2][3];
#pragma unroll
  for (int mt = 0; mt < 2; ++mt)
#pragma unroll
    for (int kq = 0; kq < 3; ++kq)
      afr[mt][kq] = *reinterpret_cast<const short8*>(
          &Asm[((wv * 2 + mt) * 16 + lrow) * PITCH + kq * 32 + lk * 8]);

#pragma unroll
  for (int nt = 0; nt < 6; ++nt) {
#pragma unroll
    for (int kq = 0; kq < 3; ++kq) {
      const short8 bfr = *reinterpret_cast<const short8*>(
          &Ht[(nt * 16 + lrow) * PITCH + kq * 32 + lk * 8]);
      acc[0][nt] = __builtin_amdgcn_mfma_f32_16x16x32_bf16(afr[0][kq], bfr,
                                                           acc[0][nt], 0, 0, 0);
      acc[1][nt] = __builtin_amdgcn_mfma_f32_16x16x32_bf16(afr[1][kq], bfr,
                                                           acc[1][nt], 0, 0, 0);
    }
  }

#pragma unroll
  for (int mt = 0; mt < 2; ++mt) {
    const int brow0 = (wv * 2 + mt) * 16 + lk * 4;
#pragma unroll
    for (int i = 0; i < 4; ++i) {
      float* yp = y + (size_t)(brow0 + i) * NC + (size_t)n * C_;
#pragma unroll
      for (int nt = 0; nt < 6; ++nt) {
        yp[nt * 16 + lrow] = acc[mt][nt][i];
      }
    }
  }
}

extern "C" void kernel_launch(void* const* d_in, const int* in_sizes, int n_in,
                              void* d_out, int out_size, void* d_ws, size_t ws_size,
                              hipStream_t stream) {
  const float* x = (const float*)d_in[0];   // [B, N, C] fp32
  const float* wc = (const float*)d_in[1];  // [N, 49, 2] fp32
  float* y = (float*)d_out;                 // [B, N, C] fp32

  const size_t need = (size_t)N_ * 1536 * sizeof(unsigned short);  // 9.63 MB
  if (ws_size >= need) {
    unsigned short* wsB = (unsigned short*)d_ws;
    hipLaunchKernelGGL(gf_hbuild_kernel, dim3(N_), dim3(128), 0, stream, wc, wsB);
    hipLaunchKernelGGL(gf_mfma2_kernel, dim3(N_), dim3(256), 0, stream, x, wsB, y);
  } else {
    hipLaunchKernelGGL(gf_mfma_kernel, dim3(N_), dim3(256), 0, stream, x, wc, y);
  }
}